// Round 3
// baseline (136.190 us; speedup 1.0000x reference)
//
#include <hip/hip_runtime.h>
#include <math.h>

// ContentLoss: 61x61 Gaussian (sigma=1) depthwise conv w/ reflect pad on
// a,b [16,3,512,512] f32; channel-mean; MSE of difference -> scalar.
//
// Exact rewrites: blur(mean_c(a-b)) once (linearity); separable 1-D x 1-D;
// radius-6 truncation (taps beyond |d|=6 are <2.3e-11 of center),
// normalized by the FULL 61-tap sum -> matches reference normalization.
//
// pass1: one WAVE per image row. 64 lanes x 8 floats = 512 (full row) so the
// +-6 horizontal halo is a lane-neighbor shuffle; reflect at lanes 0/63 uses
// the lane's own registers. No LDS, no __syncthreads, 12 float4 loads in
// flight per lane. Also zeroes d_out (replaces the memset dispatch).
// pass2: vertical blur + square + block reduce + atomicAdd.

#define R 6
#define HW 512
#define CS (HW * HW)
#define NPIX (16.0f * 512.0f * 512.0f)

typedef float f4 __attribute__((ext_vector_type(4)));

struct GaussW { float w[R + 1]; };

__global__ __launch_bounds__(256) void cl_pass1(
    const float* __restrict__ A, const float* __restrict__ B,
    float* __restrict__ T, float* __restrict__ out, GaussW gw) {
  const int tid  = threadIdx.x;
  const int lane = tid & 63;
  const int row  = (blockIdx.x << 2) + (tid >> 6);  // 0 .. 16*512-1
  const int bimg = row >> 9;
  const int y    = row & (HW - 1);
  const int x    = lane << 3;  // 8 floats per lane

  if (row == 0 && lane == 0) *out = 0.f;  // pass2 atomics start after pass1

  const size_t base = ((size_t)bimg * 3 * HW + y) * HW + (size_t)x;
  const float* pa = A + base;
  const float* pb = B + base;

  // 12 nontemporal float4 loads (3 channels x 2 tensors x 8 floats)
  f4 a00 = __builtin_nontemporal_load((const f4*)(pa));
  f4 a01 = __builtin_nontemporal_load((const f4*)(pa + 4));
  f4 a10 = __builtin_nontemporal_load((const f4*)(pa + CS));
  f4 a11 = __builtin_nontemporal_load((const f4*)(pa + CS + 4));
  f4 a20 = __builtin_nontemporal_load((const f4*)(pa + 2 * CS));
  f4 a21 = __builtin_nontemporal_load((const f4*)(pa + 2 * CS + 4));
  f4 b00 = __builtin_nontemporal_load((const f4*)(pb));
  f4 b01 = __builtin_nontemporal_load((const f4*)(pb + 4));
  f4 b10 = __builtin_nontemporal_load((const f4*)(pb + CS));
  f4 b11 = __builtin_nontemporal_load((const f4*)(pb + CS + 4));
  f4 b20 = __builtin_nontemporal_load((const f4*)(pb + 2 * CS));
  f4 b21 = __builtin_nontemporal_load((const f4*)(pb + 2 * CS + 4));

  const float inv3 = 1.0f / 3.0f;
  f4 s0 = ((a00 - b00) + (a10 - b10) + (a20 - b20)) * inv3;
  f4 s1 = ((a01 - b01) + (a11 - b11) + (a21 - b21)) * inv3;

  float ev[8] = {s0.x, s0.y, s0.z, s0.w, s1.x, s1.y, s1.z, s1.w};

  // window ew[j] = e[x - 6 + j], j = 0..19
  float ew[20];
#pragma unroll
  for (int j = 0; j < 8; ++j) ew[6 + j] = ev[j];
#pragma unroll
  for (int d = 1; d <= R; ++d) {
    // e[x-d]: lane l-1's ev[8-d]; lane 0 reflects: e[-d] = e[d] = own ev[d]
    const float v = __shfl_up(ev[8 - d], 1, 64);
    ew[6 - d] = (lane == 0) ? ev[d] : v;
  }
#pragma unroll
  for (int t = 0; t < R; ++t) {
    // e[x+8+t]: lane l+1's ev[t]; lane 63 reflects: e[512+t] = e[510-t] = own ev[6-t]
    const float u = __shfl_down(ev[t], 1, 64);
    ew[14 + t] = (lane == 63) ? ev[6 - t] : u;
  }

  float o[8];
#pragma unroll
  for (int k = 0; k < 8; ++k) {
    float acc = gw.w[0] * ew[6 + k];
#pragma unroll
    for (int d = 1; d <= R; ++d) acc += gw.w[d] * (ew[6 + k - d] + ew[6 + k + d]);
    o[k] = acc;
  }

  float* tp = T + (size_t)row * HW + x;
  *reinterpret_cast<f4*>(tp)     = (f4){o[0], o[1], o[2], o[3]};
  *reinterpret_cast<f4*>(tp + 4) = (f4){o[4], o[5], o[6], o[7]};
}

// Pass 2: vertical blur + square + reduce.
// Block = 256 threads owns (image, 256-wide x-strip, 32-row y-chunk).
__global__ __launch_bounds__(256) void cl_pass2(
    const float* __restrict__ T, float* __restrict__ out, GaussW gw) {
  const int bid  = blockIdx.x;
  const int bimg = bid >> 5;            // 32 blocks per image
  const int rem  = bid & 31;
  const int xs   = rem & 1;             // 2 x-strips of 256
  const int yc   = rem >> 1;            // 16 y-chunks of 32
  const int x    = (xs << 8) + threadIdx.x;
  const int y0   = yc << 5;

  const float* tb = T + (size_t)bimg * HW * HW;

  float acc = 0.f;
#pragma unroll 4
  for (int yy = 0; yy < 32; ++yy) {
    const int y = y0 + yy;
    float v = gw.w[0] * tb[(size_t)y * HW + x];
#pragma unroll
    for (int d = 1; d <= R; ++d) {
      int ym = y - d; ym = (ym < 0) ? -ym : ym;
      int yp = y + d; yp = (yp > HW - 1) ? (2 * (HW - 1) - yp) : yp;
      v += gw.w[d] * (tb[(size_t)ym * HW + x] + tb[(size_t)yp * HW + x]);
    }
    acc += v * v;
  }

#pragma unroll
  for (int off = 32; off > 0; off >>= 1) acc += __shfl_down(acc, off, 64);
  __shared__ float wsum[4];
  const int lane = threadIdx.x & 63;
  const int wv   = threadIdx.x >> 6;
  if (lane == 0) wsum[wv] = acc;
  __syncthreads();
  if (threadIdx.x == 0) {
    const float s = wsum[0] + wsum[1] + wsum[2] + wsum[3];
    atomicAdd(out, s * (1.0f / NPIX));
  }
}

extern "C" void kernel_launch(void* const* d_in, const int* in_sizes, int n_in,
                              void* d_out, int out_size, void* d_ws, size_t ws_size,
                              hipStream_t stream) {
  const float* A = (const float*)d_in[0];
  const float* B = (const float*)d_in[1];
  float* out = (float*)d_out;
  float* T = (float*)d_ws;  // 16*512*512 floats = 16.8 MB

  // w[d] = exp(-d^2/2) / sum_{x=0..60} exp(-(x-30)^2/2)  (full-61-tap norm)
  GaussW gw;
  {
    double S = 0.0;
    for (int i = 0; i < 61; ++i) {
      const double dd = (double)i - 30.0;
      S += exp(-dd * dd * 0.5);
    }
    for (int d = 0; d <= R; ++d)
      gw.w[d] = (float)(exp(-(double)(d * d) * 0.5) / S);
  }

  cl_pass1<<<(16 * HW) / 4, 256, 0, stream>>>(A, B, T, out, gw);
  cl_pass2<<<16 * 32, 256, 0, stream>>>(T, out, gw);
}

// Round 4
// 131.327 us; speedup vs baseline: 1.0370x; 1.0370x over previous
//
#include <hip/hip_runtime.h>
#include <math.h>

// ContentLoss: 61x61 Gaussian (sigma=1) depthwise conv w/ reflect pad on
// a,b [16,3,512,512] f32; channel-mean; MSE of difference -> scalar.
//
// Exact rewrites: blur(mean_c(a-b)) once (linearity); separable 1-D x 1-D;
// radius-6 truncation (taps beyond |d|=6 are <2.3e-11 of center),
// normalized by the FULL 61-tap sum -> matches reference normalization.
//
// pass1: one WAVE per image row (64 lanes x 8 floats = 512). Horizontal halo
// via lane-neighbor shuffles; reflect at lanes 0/63 from own registers.
// No LDS, no __syncthreads. Also zeroes d_out.
// pass2: vertical blur via 13-row REGISTER sliding window (statically-indexed
// ring, fully unrolled => no scratch). Each T element loaded exactly once
// (+ y-halo); square + block reduce + atomicAdd.

#define R 6
#define HW 512
#define CS (HW * HW)
#define CH 32
#define NPIX (16.0f * 512.0f * 512.0f)

typedef float f4 __attribute__((ext_vector_type(4)));

struct GaussW { float w[R + 1]; };

__global__ __launch_bounds__(256) void cl_pass1(
    const float* __restrict__ A, const float* __restrict__ B,
    float* __restrict__ T, float* __restrict__ out, GaussW gw) {
  const int tid  = threadIdx.x;
  const int lane = tid & 63;
  const int row  = (blockIdx.x << 2) + (tid >> 6);  // 0 .. 16*512-1
  const int bimg = row >> 9;
  const int y    = row & (HW - 1);
  const int x    = lane << 3;  // 8 floats per lane

  if (row == 0 && lane == 0) *out = 0.f;  // pass2 atomics start after pass1

  const size_t base = ((size_t)bimg * 3 * HW + y) * HW + (size_t)x;
  const float* pa = A + base;
  const float* pb = B + base;

  f4 a00 = __builtin_nontemporal_load((const f4*)(pa));
  f4 a01 = __builtin_nontemporal_load((const f4*)(pa + 4));
  f4 a10 = __builtin_nontemporal_load((const f4*)(pa + CS));
  f4 a11 = __builtin_nontemporal_load((const f4*)(pa + CS + 4));
  f4 a20 = __builtin_nontemporal_load((const f4*)(pa + 2 * CS));
  f4 a21 = __builtin_nontemporal_load((const f4*)(pa + 2 * CS + 4));
  f4 b00 = __builtin_nontemporal_load((const f4*)(pb));
  f4 b01 = __builtin_nontemporal_load((const f4*)(pb + 4));
  f4 b10 = __builtin_nontemporal_load((const f4*)(pb + CS));
  f4 b11 = __builtin_nontemporal_load((const f4*)(pb + CS + 4));
  f4 b20 = __builtin_nontemporal_load((const f4*)(pb + 2 * CS));
  f4 b21 = __builtin_nontemporal_load((const f4*)(pb + 2 * CS + 4));

  const float inv3 = 1.0f / 3.0f;
  f4 s0 = ((a00 - b00) + (a10 - b10) + (a20 - b20)) * inv3;
  f4 s1 = ((a01 - b01) + (a11 - b11) + (a21 - b21)) * inv3;

  float ev[8] = {s0.x, s0.y, s0.z, s0.w, s1.x, s1.y, s1.z, s1.w};

  float ew[20];  // ew[j] = e[x - 6 + j]
#pragma unroll
  for (int j = 0; j < 8; ++j) ew[6 + j] = ev[j];
#pragma unroll
  for (int d = 1; d <= R; ++d) {
    const float v = __shfl_up(ev[8 - d], 1, 64);
    ew[6 - d] = (lane == 0) ? ev[d] : v;   // reflect: e[-d] = e[d]
  }
#pragma unroll
  for (int t = 0; t < R; ++t) {
    const float u = __shfl_down(ev[t], 1, 64);
    ew[14 + t] = (lane == 63) ? ev[6 - t] : u;  // reflect: e[512+t] = e[510-t]
  }

  float o[8];
#pragma unroll
  for (int k = 0; k < 8; ++k) {
    float acc = gw.w[0] * ew[6 + k];
#pragma unroll
    for (int d = 1; d <= R; ++d) acc += gw.w[d] * (ew[6 + k - d] + ew[6 + k + d]);
    o[k] = acc;
  }

  float* tp = T + (size_t)row * HW + x;
  *reinterpret_cast<f4*>(tp)     = (f4){o[0], o[1], o[2], o[3]};
  *reinterpret_cast<f4*>(tp + 4) = (f4){o[4], o[5], o[6], o[7]};
}

// Pass 2: vertical blur + square + reduce. One thread per x-column,
// 32-row y-chunk, 13-row register ring (all indices compile-time).
// Grid: 16 images * 16 chunks = 256 blocks of 512 threads.
__global__ __launch_bounds__(512) void cl_pass2(
    const float* __restrict__ T, float* __restrict__ out, GaussW gw) {
  const int bid  = blockIdx.x;
  const int bimg = bid >> 4;
  const int yc   = bid & 15;
  const int x    = threadIdx.x;        // 0..511
  const int y0   = yc << 5;

  const float* tb = T + (size_t)bimg * CS + x;

  float win[13];
#pragma unroll
  for (int i = 0; i < 12; ++i) {
    int y = y0 - R + i;                // y0-6 .. y0+5 : only lower reflect possible
    y = (y < 0) ? -y : y;
    win[i] = tb[(size_t)y * HW];
  }

  float acc = 0.f;
#pragma unroll
  for (int yy = 0; yy < CH; ++yy) {
    int y = y0 + yy + R;               // y0+6 .. y0+37 : only upper reflect possible
    y = (y > HW - 1) ? (2 * (HW - 1) - y) : y;
    win[(yy + 12) % 13] = tb[(size_t)y * HW];
    float v = gw.w[6] * (win[(yy + 0) % 13] + win[(yy + 12) % 13]);
    v += gw.w[5] * (win[(yy + 1) % 13] + win[(yy + 11) % 13]);
    v += gw.w[4] * (win[(yy + 2) % 13] + win[(yy + 10) % 13]);
    v += gw.w[3] * (win[(yy + 3) % 13] + win[(yy + 9) % 13]);
    v += gw.w[2] * (win[(yy + 4) % 13] + win[(yy + 8) % 13]);
    v += gw.w[1] * (win[(yy + 5) % 13] + win[(yy + 7) % 13]);
    v += gw.w[0] *  win[(yy + 6) % 13];
    acc += v * v;
  }

  // block reduce: wave shuffle then LDS across the 8 waves
#pragma unroll
  for (int off = 32; off > 0; off >>= 1) acc += __shfl_down(acc, off, 64);
  __shared__ float wsum[8];
  const int lane = threadIdx.x & 63;
  const int wv   = threadIdx.x >> 6;
  if (lane == 0) wsum[wv] = acc;
  __syncthreads();
  if (threadIdx.x == 0) {
    float s = 0.f;
#pragma unroll
    for (int i = 0; i < 8; ++i) s += wsum[i];
    atomicAdd(out, s * (1.0f / NPIX));
  }
}

extern "C" void kernel_launch(void* const* d_in, const int* in_sizes, int n_in,
                              void* d_out, int out_size, void* d_ws, size_t ws_size,
                              hipStream_t stream) {
  const float* A = (const float*)d_in[0];
  const float* B = (const float*)d_in[1];
  float* out = (float*)d_out;
  float* T = (float*)d_ws;  // 16*512*512 floats = 16.8 MB

  // w[d] = exp(-d^2/2) / sum_{x=0..60} exp(-(x-30)^2/2)  (full-61-tap norm)
  GaussW gw;
  {
    double S = 0.0;
    for (int i = 0; i < 61; ++i) {
      const double dd = (double)i - 30.0;
      S += exp(-dd * dd * 0.5);
    }
    for (int d = 0; d <= R; ++d)
      gw.w[d] = (float)(exp(-(double)(d * d) * 0.5) / S);
  }

  cl_pass1<<<(16 * HW) / 4, 256, 0, stream>>>(A, B, T, out, gw);
  cl_pass2<<<16 * 16, 512, 0, stream>>>(T, out, gw);
}